// Round 1
// baseline (208.585 us; speedup 1.0000x reference)
//
#include <hip/hip_runtime.h>
#include <math.h>

namespace {

constexpr int kRows = 4096;
constexpr int kNF   = 65;
constexpr int kNE   = 256;
constexpr int kNH   = 8;
constexpr int kNC   = 64;                  // kNF - 1 fields used
constexpr int kXRow = kNF * kNE;           // 16640 floats per x row
constexpr int kORow = (kNF + kNH) * kNE;   // 18688 floats per out row
constexpr int kPad  = 260;                 // LDS row stride (floats): 16B-aligned, spreads banks

// w2[h*32+d] = sum_k bw[h,d,k] * query[h,k]
__global__ __launch_bounds__(256) void w2_precompute(
    const float* __restrict__ bw, const float* __restrict__ query,
    float* __restrict__ w2) {
  const int t = threadIdx.x;         // t = h*32 + d
  const int h = t >> 5;
  const float4* __restrict__ b4 = reinterpret_cast<const float4*>(bw) + (size_t)t * 64;
  const float4* __restrict__ q4 = reinterpret_cast<const float4*>(query) + (size_t)h * 64;
  float acc = 0.f;
#pragma unroll 8
  for (int k = 0; k < 64; ++k) {
    const float4 b = b4[k];
    const float4 q = q4[k];
    acc += b.x * q.x + b.y * q.y + b.z * q.z + b.w * q.w;
  }
  w2[t] = acc;
}

// One block (256 threads) per row r.
__global__ __launch_bounds__(256) void fused_row(
    const float* __restrict__ x, const float* __restrict__ w2g,
    const float* __restrict__ vals, float* __restrict__ out) {
  __shared__ float keys[kNC * kPad];   // fields 1..64, [c][e], padded stride
  __shared__ float w2s[kNH * 32];
  __shared__ float vls[kNH * kNC];
  __shared__ float cw[kNC * kNH];      // cross weights, [c][h] for b64 broadcast reads

  const int tid = threadIdx.x;
  const int r   = blockIdx.x;
  const float* __restrict__ xrow = x + (size_t)r * kXRow;
  float* __restrict__ orow       = out + (size_t)r * kORow;

  w2s[tid]       = w2g[tid];
  vls[tid]       = vals[tid];
  vls[tid + 256] = vals[tid + 256];

  // ---- phase A: stream x row -> out copy, stage fields 1..64 into LDS ----
  const float4* __restrict__ x4 = reinterpret_cast<const float4*>(xrow);
  float4* __restrict__ o4       = reinterpret_cast<float4*>(orow);
  for (int i = tid; i < kXRow / 4; i += 256) {
    const float4 v = x4[i];
    o4[i] = v;
    const int c = i >> 6;            // field index 0..64
    if (c) {
      *reinterpret_cast<float4*>(&keys[(c - 1) * kPad + (i & 63) * 4]) = v;
    }
  }
  __syncthreads();

  // ---- phase B: att (bilinear gate logits) + entmax-1.5 bisection + cross weights
  {
    const int lane = tid & 63;
    const int wv   = tid >> 6;                 // wave 0..3
    const int h    = wv * 2 + (lane >> 5);     // head handled by this half-wave
    const int c0   = lane & 31;                // this lane owns fields c0 and c0+32

    float att_a = 0.f, att_b = 0.f;
    const float4* __restrict__ wp = reinterpret_cast<const float4*>(&w2s[h * 32]);
    const float4* __restrict__ ka = reinterpret_cast<const float4*>(&keys[c0 * kPad + h * 32]);
    const float4* __restrict__ kb = reinterpret_cast<const float4*>(&keys[(c0 + 32) * kPad + h * 32]);
#pragma unroll
    for (int dq = 0; dq < 8; ++dq) {
      const float4 w = wp[dq];
      const float4 a = ka[dq];
      const float4 b = kb[dq];
      att_a += a.x * w.x + a.y * w.y + a.z * w.z + a.w * w.w;
      att_b += b.x * w.x + b.y * w.y + b.z * w.z + b.w * w.w;
    }
    // Xs = att * scale * (alpha-1);  scale = 256^-0.5 = 1/16, alpha-1 = 0.5
    const float kS = 0.0625f * 0.5f;
    const float Xa = att_a * kS;
    const float Xb = att_b * kS;

    // row max over 64 fields: local pair max + 32-lane butterfly (stays in half-wave)
    float mx = fmaxf(Xa, Xb);
#pragma unroll
    for (int off = 16; off; off >>= 1) mx = fmaxf(mx, __shfl_xor(mx, off));

    float tau_lo = mx - 1.0f;       // _gp(1, 1.5) = 1
    float dm     = 0.875f;          // tau_hi - tau_lo = 1 - (1/64)^0.5
    float ta = fmaxf(Xa - tau_lo, 0.f);
    float tb = fmaxf(Xb - tau_lo, 0.f);
    float f_lo = ta * ta + tb * tb;
#pragma unroll
    for (int off = 16; off; off >>= 1) f_lo += __shfl_xor(f_lo, off);
    f_lo -= 1.0f;

    float tau_m = tau_lo;
    for (int it = 0; it < 50; ++it) {
      dm *= 0.5f;
      tau_m = tau_lo + dm;
      float pa = fmaxf(Xa - tau_m, 0.f);
      float pb = fmaxf(Xb - tau_m, 0.f);
      float fm = pa * pa + pb * pb;
#pragma unroll
      for (int off = 16; off; off >>= 1) fm += __shfl_xor(fm, off);
      fm -= 1.0f;
      tau_lo = (fm * f_lo >= 0.f) ? tau_m : tau_lo;
      // fp32 fixed point: once tau_lo + dm/2 rounds to tau_lo (for every row in
      // this wave), every remaining reference iteration is a bitwise no-op with
      // final tau_m == tau_lo. Preserves exact fp32 semantics of the 50 iters.
      if (__all(tau_lo + dm * 0.5f == tau_lo)) {
        tau_m = tau_lo;
        break;
      }
    }

    float pa = fmaxf(Xa - tau_m, 0.f); pa *= pa;
    float pb = fmaxf(Xb - tau_m, 0.f); pb *= pb;
    float s = pa + pb;
#pragma unroll
    for (int off = 16; off; off >>= 1) s += __shfl_xor(s, off);

    cw[c0 * kNH + h]        = (pa / s) * vls[h * kNC + c0];
    cw[(c0 + 32) * kNH + h] = (pb / s) * vls[h * kNC + c0 + 32];
  }
  __syncthreads();

  // ---- phase C: x_cross[h][e] = exp( sum_c keys[c][e] * cw[c][h] ) ----
  {
    const int q  = tid & 63;          // e-quad: e = 4q..4q+3
    const int h0 = (tid >> 6) * 2;    // this thread does heads h0, h0+1
    float4 acc0 = {0.f, 0.f, 0.f, 0.f};
    float4 acc1 = {0.f, 0.f, 0.f, 0.f};
#pragma unroll 8
    for (int c = 0; c < kNC; ++c) {
      const float4 v = *reinterpret_cast<const float4*>(&keys[c * kPad + q * 4]);
      const float2 w = *reinterpret_cast<const float2*>(&cw[c * kNH + h0]);
      acc0.x += w.x * v.x; acc0.y += w.x * v.y; acc0.z += w.x * v.z; acc0.w += w.x * v.w;
      acc1.x += w.y * v.x; acc1.y += w.y * v.y; acc1.z += w.y * v.z; acc1.w += w.y * v.w;
    }
    float4 e0, e1;
    e0.x = expf(acc0.x); e0.y = expf(acc0.y); e0.z = expf(acc0.z); e0.w = expf(acc0.w);
    e1.x = expf(acc1.x); e1.y = expf(acc1.y); e1.z = expf(acc1.z); e1.w = expf(acc1.w);
    *reinterpret_cast<float4*>(&orow[kXRow + h0 * kNE + q * 4])       = e0;
    *reinterpret_cast<float4*>(&orow[kXRow + (h0 + 1) * kNE + q * 4]) = e1;
  }
}

}  // namespace

extern "C" void kernel_launch(void* const* d_in, const int* in_sizes, int n_in,
                              void* d_out, int out_size, void* d_ws, size_t ws_size,
                              hipStream_t stream) {
  const float* x     = reinterpret_cast<const float*>(d_in[0]);
  const float* bw    = reinterpret_cast<const float*>(d_in[1]);
  const float* query = reinterpret_cast<const float*>(d_in[2]);
  const float* vals  = reinterpret_cast<const float*>(d_in[3]);
  float* out = reinterpret_cast<float*>(d_out);
  float* w2  = reinterpret_cast<float*>(d_ws);   // 256 floats of scratch

  hipLaunchKernelGGL(w2_precompute, dim3(1), dim3(256), 0, stream, bw, query, w2);
  hipLaunchKernelGGL(fused_row, dim3(kRows), dim3(256), 0, stream, x, w2, vals, out);
}

// Round 2
// 196.833 us; speedup vs baseline: 1.0597x; 1.0597x over previous
//
#include <hip/hip_runtime.h>
#include <math.h>

namespace {

constexpr int kRows = 4096;
constexpr int kNF   = 65;
constexpr int kNE   = 256;
constexpr int kNH   = 8;
constexpr int kNC   = 64;                  // kNF - 1 fields used
constexpr int kXRow = kNF * kNE;           // 16640 floats per x row
constexpr int kORow = (kNF + kNH) * kNE;   // 18688 floats per out row

// w2[h*32+d] = sum_k bw[h,d,k] * query[h,k]
__global__ __launch_bounds__(256) void w2_precompute(
    const float* __restrict__ bw, const float* __restrict__ query,
    float* __restrict__ w2) {
  const int t = threadIdx.x;         // t = h*32 + d
  const int h = t >> 5;
  const float4* __restrict__ b4 = reinterpret_cast<const float4*>(bw) + (size_t)t * 64;
  const float4* __restrict__ q4 = reinterpret_cast<const float4*>(query) + (size_t)h * 64;
  float acc = 0.f;
#pragma unroll 8
  for (int k = 0; k < 64; ++k) {
    const float4 b = b4[k];
    const float4 q = q4[k];
    acc += b.x * q.x + b.y * q.y + b.z * q.z + b.w * q.w;
  }
  w2[t] = acc;
}

// One WAVE per row; 4 rows per 256-thread block. No inter-wave dependencies
// after the initial w2/vls load. Keys are re-read from global (L1/L2-hot after
// the copy pass) instead of a 64 KB LDS tile -> LDS 70 KB -> ~19 KB, so all
// 1024 blocks are co-resident (4 blocks/CU, 16 waves/CU).
__global__ __launch_bounds__(256, 4) void fused_row(
    const float* __restrict__ x, const float* __restrict__ w2g,
    const float* __restrict__ vals, float* __restrict__ out) {
  __shared__ float w2s[kNH * 32];          // 1 KB
  __shared__ float vls[kNH * kNC];         // 2 KB
  __shared__ float att_t[4][kNC * kNH];    // per-wave transpose patch, 8 KB
  __shared__ float cwp[4][kNC * kNH];      // per-wave cross weights [c][h], 8 KB

  const int tid  = threadIdx.x;
  const int wv   = tid >> 6;
  const int lane = tid & 63;
  const int r    = blockIdx.x * 4 + wv;

  w2s[tid]       = w2g[tid];
  vls[tid]       = vals[tid];
  vls[tid + 256] = vals[tid + 256];
  __syncthreads();

  const float* __restrict__ xrow = x + (size_t)r * kXRow;
  float* __restrict__ orow       = out + (size_t)r * kORow;

  // ---- phase A: stream copy x row -> out (also warms L1/L2 with the row) ----
  {
    const float4* __restrict__ x4 = reinterpret_cast<const float4*>(xrow);
    float4* __restrict__ o4       = reinterpret_cast<float4*>(orow);
#pragma unroll 5
    for (int i = lane; i < kXRow / 4; i += 64) o4[i] = x4[i];
  }

  // ---- phase B: att for all 8 heads; lane = field c (reads its 1 KB slice) ----
  {
    float att[kNH];
#pragma unroll
    for (int h = 0; h < kNH; ++h) att[h] = 0.f;
    const float4* __restrict__ k4 =
        reinterpret_cast<const float4*>(xrow + (size_t)(lane + 1) * kNE);
    const float4* __restrict__ w4 = reinterpret_cast<const float4*>(w2s);
#pragma unroll 8
    for (int eq = 0; eq < 64; ++eq) {
      const float4 k = k4[eq];
      const float4 w = w4[eq];        // broadcast LDS read, conflict-free
      att[eq >> 3] += k.x * w.x + k.y * w.y + k.z * w.z + k.w * w.w;
    }
    // Xs = att * scale * (alpha-1) = att * (1/16) * 0.5
    const float kS = 0.03125f;
    float* at = att_t[wv];
#pragma unroll
    for (int h = 0; h < kNH; ++h) at[lane * kNH + h] = att[h] * kS;
  }
  // wave-private LDS region: per-wave ds ordering suffices, no barrier.

  // ---- entmax-1.5 bisection, 8 heads in parallel: lane = h*8 + k, 8 c's/lane
  {
    const int h  = lane >> 3;
    const int kk = lane & 7;
    const float* at = att_t[wv];
    float X[8];
#pragma unroll
    for (int j = 0; j < 8; ++j) X[j] = at[(kk * 8 + j) * kNH + h];

    float mx = X[0];
#pragma unroll
    for (int j = 1; j < 8; ++j) mx = fmaxf(mx, X[j]);
    mx = fmaxf(mx, __shfl_xor(mx, 1));
    mx = fmaxf(mx, __shfl_xor(mx, 2));
    mx = fmaxf(mx, __shfl_xor(mx, 4));

    float tau_lo = mx - 1.0f;       // _gp(1, 1.5) = 1
    float dm     = 0.875f;          // 1 - (1/64)^0.5
    float f_lo = 0.f;
#pragma unroll
    for (int j = 0; j < 8; ++j) {
      float t = fmaxf(X[j] - tau_lo, 0.f);
      f_lo += t * t;
    }
    f_lo += __shfl_xor(f_lo, 1);
    f_lo += __shfl_xor(f_lo, 2);
    f_lo += __shfl_xor(f_lo, 4);
    f_lo -= 1.0f;

    float tau_m = tau_lo;
    for (int it = 0; it < 50; ++it) {
      dm *= 0.5f;
      tau_m = tau_lo + dm;
      float fm = 0.f;
#pragma unroll
      for (int j = 0; j < 8; ++j) {
        float t = fmaxf(X[j] - tau_m, 0.f);
        fm += t * t;
      }
      fm += __shfl_xor(fm, 1);
      fm += __shfl_xor(fm, 2);
      fm += __shfl_xor(fm, 4);
      fm -= 1.0f;
      tau_lo = (fm * f_lo >= 0.f) ? tau_m : tau_lo;
      // fp32 fixed point: once tau_lo + dm/2 rounds to tau_lo for every lane,
      // all remaining reference iterations are bitwise no-ops with final
      // tau_m == tau_lo. Exact fp32 semantics preserved (verified round 1).
      if (__all(tau_lo + dm * 0.5f == tau_lo)) {
        tau_m = tau_lo;
        break;
      }
    }

    float p[8];
    float s = 0.f;
#pragma unroll
    for (int j = 0; j < 8; ++j) {
      float t = fmaxf(X[j] - tau_m, 0.f);
      p[j] = t * t;
      s += p[j];
    }
    s += __shfl_xor(s, 1);
    s += __shfl_xor(s, 2);
    s += __shfl_xor(s, 4);
    const float inv = 1.0f / s;
    float* cw = cwp[wv];
#pragma unroll
    for (int j = 0; j < 8; ++j) {
      const int c = kk * 8 + j;
      cw[c * kNH + h] = p[j] * inv * vls[h * kNC + c];
    }
  }

  // ---- phase C: x_cross[h][e] = exp( sum_c keys[c][e] * cw[c][h] ) ----
  {
    const float4* __restrict__ k4 =
        reinterpret_cast<const float4*>(xrow + kNE);   // field 1 start
    const float4* cw4 = reinterpret_cast<const float4*>(cwp[wv]);
    float4 acc[kNH];
#pragma unroll
    for (int h = 0; h < kNH; ++h) acc[h] = make_float4(0.f, 0.f, 0.f, 0.f);
#pragma unroll 8
    for (int c = 0; c < kNC; ++c) {
      const float4 kv = k4[(size_t)c * 64 + lane];     // coalesced 1 KB / instr
      const float4 ca = cw4[c * 2];                    // broadcast
      const float4 cb = cw4[c * 2 + 1];
      acc[0].x += ca.x * kv.x; acc[0].y += ca.x * kv.y; acc[0].z += ca.x * kv.z; acc[0].w += ca.x * kv.w;
      acc[1].x += ca.y * kv.x; acc[1].y += ca.y * kv.y; acc[1].z += ca.y * kv.z; acc[1].w += ca.y * kv.w;
      acc[2].x += ca.z * kv.x; acc[2].y += ca.z * kv.y; acc[2].z += ca.z * kv.z; acc[2].w += ca.z * kv.w;
      acc[3].x += ca.w * kv.x; acc[3].y += ca.w * kv.y; acc[3].z += ca.w * kv.z; acc[3].w += ca.w * kv.w;
      acc[4].x += cb.x * kv.x; acc[4].y += cb.x * kv.y; acc[4].z += cb.x * kv.z; acc[4].w += cb.x * kv.w;
      acc[5].x += cb.y * kv.x; acc[5].y += cb.y * kv.y; acc[5].z += cb.y * kv.z; acc[5].w += cb.y * kv.w;
      acc[6].x += cb.z * kv.x; acc[6].y += cb.z * kv.y; acc[6].z += cb.z * kv.z; acc[6].w += cb.z * kv.w;
      acc[7].x += cb.w * kv.x; acc[7].y += cb.w * kv.y; acc[7].z += cb.w * kv.z; acc[7].w += cb.w * kv.w;
    }
#pragma unroll
    for (int h = 0; h < kNH; ++h) {
      float4 e;
      e.x = expf(acc[h].x); e.y = expf(acc[h].y);
      e.z = expf(acc[h].z); e.w = expf(acc[h].w);
      *reinterpret_cast<float4*>(&orow[kXRow + h * kNE + lane * 4]) = e;
    }
  }
}

}  // namespace

extern "C" void kernel_launch(void* const* d_in, const int* in_sizes, int n_in,
                              void* d_out, int out_size, void* d_ws, size_t ws_size,
                              hipStream_t stream) {
  const float* x     = reinterpret_cast<const float*>(d_in[0]);
  const float* bw    = reinterpret_cast<const float*>(d_in[1]);
  const float* query = reinterpret_cast<const float*>(d_in[2]);
  const float* vals  = reinterpret_cast<const float*>(d_in[3]);
  float* out = reinterpret_cast<float*>(d_out);
  float* w2  = reinterpret_cast<float*>(d_ws);   // 256 floats of scratch

  hipLaunchKernelGGL(w2_precompute, dim3(1), dim3(256), 0, stream, bw, query, w2);
  hipLaunchKernelGGL(fused_row, dim3(kRows / 4), dim3(256), 0, stream, x, w2, vals, out);
}